// Round 7
// baseline (373.156 us; speedup 1.0000x reference)
//
#include <hip/hip_runtime.h>
#include <cmath>

// FullyConnectedTensorProductRescaleSwishGate — MI355X bf16-MFMA, round 7.
//
// R7 fixes vs R6 (both counter-driven):
//  1) NT cache policy on the streaming traffic (x DMA aux=NT, out stores
//     nontemporal) so the 426 KB weight set stays L2-resident — R6's FETCH
//     (673 MB vs 258 MB ideal) showed weights being re-fetched from L3/HBM.
//  2) vmcnt is IN-ORDER (oldest-first): R6 issued the 80 KB x-DMA before the
//     compute B-loads, so every B-frag wait also drained the DMA (~3.3 us,
//     HBM-BW-bound) — serialized in front of the MFMAs. Now the DMA is issued
//     AFTER the last B-load (sched_barrier pinned); compute's vmcnt stream is
//     pure in-order B-loads; the DMA drains at the next tile's barrier.
//     Bias values hoisted to registers (an epilogue bias load would re-poison).
//
// Schedule per tile: bar -> convert Xstage->Abuf -> bar -> compute (clean
// vmcnt) -> issue DMA(t+1) -> epilogue (regs + Ystage + nt stores) -> loop.
//
// Math (per row): features A (K=768) = [x0 | dot=x1*y1 | x1_0 | x1_1 | x1_2]
//   u0=x0@C0W0, d1=dot@C1W1, u2=x0@C2W2, d3=dot@C3W3, u4=x0@C4W4,
//   r_i=x1_i@C5W5, q_i=x1_i@C6W6
//   s1=y0*u0+d1 ; s2=y0*u2+d3 ; v_i=y1_i*u4+y0*r_i+y1_{j2}*q_{j1}-y1_{j1}*q_{j2}

typedef __bf16 bf16_t;
typedef bf16_t bf16x8 __attribute__((ext_vector_type(8)));
typedef bf16_t bf16x4 __attribute__((ext_vector_type(4)));
typedef float  f32x4  __attribute__((ext_vector_type(4)));

#define BM 32
#define KP 768          // feature row stride (elems) = 1536 B
#define NBLK 256        // persistent blocks (1 per CU)

// weight group offsets in d_ws (bf16 elems), stored [col][k], pre-scaled
#define WU0 0           // 256 x 256
#define WD1 65536       // 256 x 128
#define WU2 98304       // 128 x 256
#define WD3 131072      // 128 x 128
#define WU4 147456      // 128 x 256
#define WR  180224      // 128 x 128
#define WQ  196608      // 128 x 128
#define WTOT 212992

#define MFMA(acc, av, bv) acc = __builtin_amdgcn_mfma_f32_16x16x32_bf16(av, bv, acc, 0, 0, 0)

// async global->LDS DMA, 16 B/lane. aux: 0 = cached, 2 = NT (evict-first,
// keeps streaming x out of L2 so weights stay resident).
__device__ __forceinline__ void async_copy16_nt(const float* g, float* l)
{
    __builtin_amdgcn_global_load_lds(
        (const __attribute__((address_space(1))) void*)g,
        (__attribute__((address_space(3))) void*)l, 16, 0, 2);
}
__device__ __forceinline__ void async_copy16(const float* g, float* l)
{
    __builtin_amdgcn_global_load_lds(
        (const __attribute__((address_space(1))) void*)g,
        (__attribute__((address_space(3))) void*)l, 16, 0, 0);
}

__global__ void prep_weights(const float* __restrict__ W0, const float* __restrict__ W1,
                             const float* __restrict__ W2, const float* __restrict__ W3,
                             const float* __restrict__ W4, const float* __restrict__ W5,
                             const float* __restrict__ W6, bf16_t* __restrict__ WT,
                             float c0, float c1, float c2, float c3,
                             float c4, float c5, float c6)
{
    int idx = blockIdx.x * 256 + threadIdx.x;
    if (idx >= WTOT) return;
    float v;
    if (idx < WD1)      { int c = idx >> 8, k = idx & 255;                    v = c0 * W0[k * 256 + c]; }
    else if (idx < WU2) { int j = idx - WD1; int c = j >> 7, k = j & 127;     v = c1 * W1[k * 256 + c]; }
    else if (idx < WD3) { int j = idx - WU2; int c = j >> 8, k = j & 255;     v = c2 * W2[k * 128 + c]; }
    else if (idx < WU4) { int j = idx - WD3; int c = j >> 7, k = j & 127;     v = c3 * W3[k * 128 + c]; }
    else if (idx < WR)  { int j = idx - WU4; int c = j >> 8, k = j & 255;     v = c4 * W4[k * 128 + c]; }
    else if (idx < WQ)  { int j = idx - WR;  int c = j >> 7, k = j & 127;     v = c5 * W5[k * 128 + c]; }
    else                { int j = idx - WQ;  int c = j >> 7, k = j & 127;     v = c6 * W6[k * 128 + c]; }
    WT[idx] = (bf16_t)v;
}

__global__ __launch_bounds__(512, 2) void tp_fused(
    const float* __restrict__ x, const float* __restrict__ y,
    const float* __restrict__ bias, const bf16_t* __restrict__ WT,
    float* __restrict__ out, int NT, float inv, float silu_c, float sig_c)
{
    __shared__ __attribute__((aligned(16))) bf16_t Abuf[BM * KP];      // 48 KB
    __shared__ __attribute__((aligned(16))) float  Xstage[BM * 640];   // 80 KB
    __shared__ __attribute__((aligned(16))) float  Ystage[2][BM * 4];  // 1 KB (dbuf)

    const int tid = threadIdx.x;
    const int l   = tid & 63;
    const int w   = tid >> 6;          // wave 0..7
    const int l15 = l & 15;
    const int lg  = l >> 4;            // lane group 0..3
    const int klane = lg * 8;
    const int asw   = (l15 & 7) << 3;  // XOR bank swizzle
    const int a0base = l15 * KP;
    const int a1base = (16 + l15) * KP;
    const int r0q = tid >> 5;          // x1-conversion row (s=0; s=1: +16)
    const int uq  = (tid & 31) * 4;    // triplet base index

    // B pointers — loop-invariant, L2-resident with NT streaming protecting L2
    const bf16_t* b0p = WT + WU0 + ((w    ) * 16 + l15) * 256 + klane;
    const bf16_t* b1p = WT + WU0 + ((w + 8) * 16 + l15) * 256 + klane;
    const bf16_t* d0p = WT + WD1 + ((w    ) * 16 + l15) * 128 + klane;
    const bf16_t* d1p = WT + WD1 + ((w + 8) * 16 + l15) * 128 + klane;
    const bf16_t* pu2 = WT + WU2 + (w * 16 + l15) * 256 + klane;
    const bf16_t* pd3 = WT + WD3 + (w * 16 + l15) * 128 + klane;
    const bf16_t* pu4 = WT + WU4 + (w * 16 + l15) * 256 + klane;
    const bf16_t* pr  = WT + WR  + (w * 16 + l15) * 128 + klane;
    const bf16_t* pq  = WT + WQ  + (w * 16 + l15) * 128 + klane;

    const int bid = blockIdx.x;
    const int NTL = (NT - bid + NBLK - 1) / NBLK;   // tiles for this block
    if (NTL <= 0) return;

    // bias hoisted to registers (loop-invariant; an epilogue load would sit on
    // vmcnt AFTER the DMA issue and force an early DMA drain)
    const float bias_s0 = bias[(w    ) * 16 + l15];
    const float bias_s1 = bias[(w + 8) * 16 + l15];
    const float bias_v  = bias[256 + w * 16 + l15];

    // ---- async DMA of tile t: x (80 KB, NT) + y (512 B) -> LDS ----
    auto DMA = [&](int t, int p) {
        const float* xb = x + (size_t)t * (BM * 640);
        const int fb = w * 2560 + l * 4;            // wave chunk 10 KB, lane*16B
        #pragma unroll
        for (int i = 0; i < 10; ++i)
            async_copy16_nt(xb + fb + i * 256, &Xstage[fb + i * 256]);
        if (w == 0 && l < 32)
            async_copy16(y + (size_t)t * (BM * 4) + l * 4, &Ystage[p][l * 4]);
    };

    DMA(bid, 0);

    for (int j = 0; j < NTL; ++j) {
        const int t = bid + j * NBLK;
        const int p = j & 1;
        __syncthreads();        // drains DMA(t); Abuf free (prev compute done)

        // ---- convert: Xstage f32 -> Abuf bf16 features (swizzled) ----
        #pragma unroll
        for (int it = 0; it < 4; ++it) {            // x0 block
            int f4 = tid + it * 512; int r = f4 >> 6, c4 = f4 & 63;
            f32x4 xv = *(const f32x4*)&Xstage[r * 640 + c4 * 4];
            bf16x4 o;
            o[0] = (bf16_t)xv[0]; o[1] = (bf16_t)xv[1];
            o[2] = (bf16_t)xv[2]; o[3] = (bf16_t)xv[3];
            *(bf16x4*)&Abuf[r * KP + ((c4 * 4) ^ ((r & 7) << 3))] = o;
        }
        #pragma unroll
        for (int s = 0; s < 2; ++s) {               // dot + x1 de-interleave
            int r = r0q + s * 16;
            const float* xp = &Xstage[r * 640 + 256 + (tid & 31) * 12];
            f32x4 A0 = *(const f32x4*)(xp);
            f32x4 A1 = *(const f32x4*)(xp + 4);
            f32x4 A2 = *(const f32x4*)(xp + 8);
            const float* yv = &Ystage[p][r * 4];
            float y1 = yv[1], y2 = yv[2], y3 = yv[3];
            int sw = (r & 7) << 3, base = r * KP;
            bf16x4 dq, e0, e1, e2;
            dq[0] = (bf16_t)(A0[0]*y1 + A0[1]*y2 + A0[2]*y3);
            dq[1] = (bf16_t)(A0[3]*y1 + A1[0]*y2 + A1[1]*y3);
            dq[2] = (bf16_t)(A1[2]*y1 + A1[3]*y2 + A2[0]*y3);
            dq[3] = (bf16_t)(A2[1]*y1 + A2[2]*y2 + A2[3]*y3);
            e0[0]=(bf16_t)A0[0]; e0[1]=(bf16_t)A0[3]; e0[2]=(bf16_t)A1[2]; e0[3]=(bf16_t)A2[1];
            e1[0]=(bf16_t)A0[1]; e1[1]=(bf16_t)A1[0]; e1[2]=(bf16_t)A1[3]; e1[3]=(bf16_t)A2[2];
            e2[0]=(bf16_t)A0[2]; e2[1]=(bf16_t)A1[1]; e2[2]=(bf16_t)A2[0]; e2[3]=(bf16_t)A2[3];
            *(bf16x4*)&Abuf[base + ((256 + uq) ^ sw)] = dq;
            *(bf16x4*)&Abuf[base + ((384 + uq) ^ sw)] = e0;
            *(bf16x4*)&Abuf[base + ((512 + uq) ^ sw)] = e1;
            *(bf16x4*)&Abuf[base + ((640 + uq) ^ sw)] = e2;
        }
        __syncthreads();        // Abuf ready; Xstage free for next DMA

        // ---- compute: vmcnt stream is PURE in-order B-loads ----
        f32x4 sU[2][2], sD[2][2], vU2[2], vD3[2], vU4[2], vR[3][2], vQ[3][2];
        {
            f32x4 z = {0.f, 0.f, 0.f, 0.f};
            #pragma unroll
            for (int a = 0; a < 2; ++a)
                #pragma unroll
                for (int b = 0; b < 2; ++b) { sU[a][b] = z; sD[a][b] = z; }
            #pragma unroll
            for (int a = 0; a < 2; ++a) { vU2[a] = z; vD3[a] = z; vU4[a] = z; }
            #pragma unroll
            for (int i = 0; i < 3; ++i)
                #pragma unroll
                for (int a = 0; a < 2; ++a) { vR[i][a] = z; vQ[i][a] = z; }
        }

        #pragma unroll
        for (int kk = 0; kk < 8; ++kk) {            // x0 block (K 0..255)
            bf16x8 a0 = *(const bf16x8*)&Abuf[a0base + ((kk * 32 + klane) ^ asw)];
            bf16x8 a1 = *(const bf16x8*)&Abuf[a1base + ((kk * 32 + klane) ^ asw)];
            bf16x8 bb;
            bb = *(const bf16x8*)(b0p + kk * 32); MFMA(sU[0][0], a0, bb); MFMA(sU[0][1], a1, bb);
            bb = *(const bf16x8*)(b1p + kk * 32); MFMA(sU[1][0], a0, bb); MFMA(sU[1][1], a1, bb);
            bb = *(const bf16x8*)(pu2 + kk * 32); MFMA(vU2[0], a0, bb); MFMA(vU2[1], a1, bb);
            bb = *(const bf16x8*)(pu4 + kk * 32); MFMA(vU4[0], a0, bb); MFMA(vU4[1], a1, bb);
        }
        #pragma unroll
        for (int kk = 0; kk < 4; ++kk) {            // dot block (K 256..383)
            bf16x8 a0 = *(const bf16x8*)&Abuf[a0base + ((256 + kk * 32 + klane) ^ asw)];
            bf16x8 a1 = *(const bf16x8*)&Abuf[a1base + ((256 + kk * 32 + klane) ^ asw)];
            bf16x8 bb;
            bb = *(const bf16x8*)(d0p + kk * 32); MFMA(sD[0][0], a0, bb); MFMA(sD[0][1], a1, bb);
            bb = *(const bf16x8*)(d1p + kk * 32); MFMA(sD[1][0], a0, bb); MFMA(sD[1][1], a1, bb);
            bb = *(const bf16x8*)(pd3 + kk * 32); MFMA(vD3[0], a0, bb); MFMA(vD3[1], a1, bb);
        }
        #pragma unroll
        for (int kk = 0; kk < 4; ++kk) {            // x1 blocks; W5/W6 frags shared over i
            bf16x8 brr = *(const bf16x8*)(pr + kk * 32);
            bf16x8 bqq = *(const bf16x8*)(pq + kk * 32);
            #pragma unroll
            for (int i = 0; i < 3; ++i) {
                int kb = 384 + i * 128 + kk * 32;
                bf16x8 a0 = *(const bf16x8*)&Abuf[a0base + ((kb + klane) ^ asw)];
                bf16x8 a1 = *(const bf16x8*)&Abuf[a1base + ((kb + klane) ^ asw)];
                MFMA(vR[i][0], a0, brr); MFMA(vR[i][1], a1, brr);
                MFMA(vQ[i][0], a0, bqq); MFMA(vQ[i][1], a1, bqq);
            }
        }

        // ---- issue next tile's DMA AFTER all B-loads (in-order vmcnt safe);
        //      sched_barriers pin it here so the compiler can't hoist it ----
        __builtin_amdgcn_sched_barrier(0);
        if (j + 1 < NTL) DMA(t + NBLK, p ^ 1);
        __builtin_amdgcn_sched_barrier(0);

        // ---- epilogue S (registers + Ystage + NT stores only) ----
        const int rowb = t * BM;
        #pragma unroll
        for (int cs = 0; cs < 2; ++cs) {
            int col = (w + 8 * cs) * 16 + l15;
            float bv = cs ? bias_s1 : bias_s0;
            #pragma unroll
            for (int rt = 0; rt < 2; ++rt)
                #pragma unroll
                for (int rg = 0; rg < 4; ++rg) {
                    int lr = rt * 16 + lg * 4 + rg;
                    float sv = (Ystage[p][lr * 4] * sU[cs][rt][rg] + sD[cs][rt][rg]) * inv + bv;
                    __builtin_nontemporal_store(silu_c * sv / (1.0f + __expf(-sv)),
                                                &out[(size_t)(rowb + lr) * 640 + col]);
                }
        }
        // ---- epilogue V (gate + cross recombination) ----
        {
            int col = w * 16 + l15;
            #pragma unroll
            for (int rt = 0; rt < 2; ++rt)
                #pragma unroll
                for (int rg = 0; rg < 4; ++rg) {
                    int lr = rt * 16 + lg * 4 + rg;
                    f32x4 yv = *(const f32x4*)&Ystage[p][lr * 4];
                    float sv = (yv[0] * vU2[rt][rg] + vD3[rt][rg]) * inv + bias_v;
                    float g  = sig_c * inv / (1.0f + __expf(-sv));
                    float u4v = vU4[rt][rg];
                    float v0 = yv[1] * u4v + yv[0] * vR[0][rt][rg] + yv[3] * vQ[1][rt][rg] - yv[2] * vQ[2][rt][rg];
                    float v1 = yv[2] * u4v + yv[0] * vR[1][rt][rg] + yv[1] * vQ[2][rt][rg] - yv[3] * vQ[0][rt][rg];
                    float v2 = yv[3] * u4v + yv[0] * vR[2][rt][rg] + yv[2] * vQ[0][rt][rg] - yv[1] * vQ[1][rt][rg];
                    size_t base = (size_t)(rowb + lr) * 640 + 256 + col * 3;
                    __builtin_nontemporal_store(v0 * g, &out[base + 0]);
                    __builtin_nontemporal_store(v1 * g, &out[base + 1]);
                    __builtin_nontemporal_store(v2 * g, &out[base + 2]);
                }
        }
    }
}

extern "C" void kernel_launch(void* const* d_in, const int* in_sizes, int n_in,
                              void* d_out, int out_size, void* d_ws, size_t ws_size,
                              hipStream_t stream)
{
    (void)n_in; (void)out_size; (void)ws_size;
    const float* x  = (const float*)d_in[0];
    const float* y  = (const float*)d_in[1];
    const float* W0 = (const float*)d_in[2];
    const float* W1 = (const float*)d_in[3];
    const float* W2 = (const float*)d_in[4];
    const float* W3 = (const float*)d_in[5];
    const float* W4 = (const float*)d_in[6];
    const float* W5 = (const float*)d_in[7];
    const float* W6 = (const float*)d_in[8];
    const float* b  = (const float*)d_in[9];
    float* out = (float*)d_out;

    const int n  = in_sizes[0] / 640;               // 100000
    const int NT = n / BM;                          // 3125 row-tiles

    bf16_t* WT = (bf16_t*)d_ws;                     // 212,992 bf16 = 425,984 B

    const double c0 = std::sqrt(256.0 * 256.0 / 384.0);
    const double c1 = std::sqrt(256.0 * 128.0 / 384.0) / std::sqrt(3.0);
    const double c2 = std::sqrt(128.0 * 256.0 / 384.0);
    const double c3 = std::sqrt(128.0 * 128.0 / 384.0) / std::sqrt(3.0);
    const double c4 = std::sqrt(3.0 * 128.0 * 256.0 / 512.0) / std::sqrt(3.0);
    const double c5 = std::sqrt(3.0 * 128.0 * 128.0 / 512.0) / std::sqrt(3.0);
    const double c6 = std::sqrt(3.0 * 128.0 * 128.0 / 512.0) / std::sqrt(6.0);
    const double inv = 1.0 / std::sqrt(2560.0);

    // second moments of silu/sigmoid under N(0,1) via Simpson (matches hermgauss)
    double m_silu = 0.0, m_sig = 0.0;
    {
        const int M = 24000;
        const double a = -12.0, h = 24.0 / M;
        for (int k = 0; k <= M; ++k) {
            double t = a + h * k;
            double wgt = (k == 0 || k == M) ? 1.0 : ((k & 1) ? 4.0 : 2.0);
            double sg = 1.0 / (1.0 + std::exp(-t));
            double phi = std::exp(-0.5 * t * t) * 0.3989422804014327;
            m_silu += wgt * (t * sg) * (t * sg) * phi;
            m_sig  += wgt * sg * sg * phi;
        }
        m_silu *= h / 3.0; m_sig *= h / 3.0;
    }
    const float silu_c = (float)(1.0 / std::sqrt(m_silu));
    const float sig_c  = (float)(1.0 / std::sqrt(m_sig));

    prep_weights<<<(WTOT + 255) / 256, 256, 0, stream>>>(
        W0, W1, W2, W3, W4, W5, W6, WT,
        (float)c0, (float)c1, (float)c2, (float)c3, (float)c4, (float)c5, (float)c6);

    int grid = NT < NBLK ? NT : NBLK;
    tp_fused<<<grid, 512, 0, stream>>>(x, y, b, WT, out, NT,
                                       (float)inv, silu_c, sig_c);
}